// Round 9
// baseline (922.587 us; speedup 1.0000x reference)
//
#include <hip/hip_runtime.h>
#include <hip/hip_bf16.h>

// Model dims
#define EMB 512
#define NW  64
#define SEQ 65            // NW+1
#define NH  8
#define DH  64
#define NL  4
#define FF_ 2048
#define VOCAB 50257
#define BS  16
#define TOK (BS*SEQ)      // 1040
#define TOUT (BS*NW)      // 1024
#define MT32 ((TOK + 31) / 32)   // 33 m-tiles of 32 rows

typedef short short8  __attribute__((ext_vector_type(8)));
typedef unsigned short ushort8n __attribute__((ext_vector_type(8)));
typedef float f32x4   __attribute__((ext_vector_type(4)));

__device__ __forceinline__ unsigned short f2bf(float f) {
    unsigned u = __float_as_uint(f);
    return (unsigned short)((u + 0x7FFF + ((u >> 16) & 1)) >> 16);  // RNE
}

template<int N> __device__ __forceinline__ void wait_vm() {
    asm volatile("s_waitcnt vmcnt(%0)" :: "n"(N) : "memory");
}

constexpr int ilog2c(int v) { return v == 32 ? 5 : v == 64 ? 6 : v == 128 ? 7 : 0; }

// ======== weight/table fp32 -> bf16 conversion ========
#define SZ_WQKV (NL*3*EMB*EMB)
#define SZ_WO   (NL*EMB*EMB)
#define SZ_W1   (NL*FF_*EMB)
#define SZ_W2   (NL*EMB*FF_)
#define SZ_TAB  (VOCAB*EMB)
#define CVT_TOTAL (SZ_WQKV+SZ_WO+SZ_W1+SZ_W2+SZ_TAB)
#define O_WO   (SZ_WQKV)
#define O_W1   (O_WO+SZ_WO)
#define O_W2   (O_W1+SZ_W1)
#define O_TAB  (O_W2+SZ_W2)

__global__ void cvt_kernel(const float* __restrict__ wqkv, const float* __restrict__ wo,
                           const float* __restrict__ w1, const float* __restrict__ w2,
                           const float* __restrict__ table, unsigned short* __restrict__ dst) {
    const int U = CVT_TOTAL / 8;
    for (int u = blockIdx.x * blockDim.x + threadIdx.x; u < U; u += gridDim.x * blockDim.x) {
        size_t elem = (size_t)u * 8;
        const float* src; size_t loc = elem;
        if      (elem < O_WO)  { src = wqkv; }
        else if (elem < O_W1)  { src = wo;    loc = elem - O_WO; }
        else if (elem < O_W2)  { src = w1;    loc = elem - O_W1; }
        else if (elem < O_TAB) { src = w2;    loc = elem - O_W2; }
        else                   { src = table; loc = elem - O_TAB; }
        float4 f0 = *(const float4*)(src + loc);
        float4 f1 = *(const float4*)(src + loc + 4);
        ushort8n o;
        o[0]=f2bf(f0.x); o[1]=f2bf(f0.y); o[2]=f2bf(f0.z); o[3]=f2bf(f0.w);
        o[4]=f2bf(f1.x); o[5]=f2bf(f1.y); o[6]=f2bf(f1.z); o[7]=f2bf(f1.w);
        *(ushort8n*)(dst + elem) = o;
    }
}

// ---------------- embed
__global__ void embed_kernel(const float* __restrict__ w_emb,
                             const float* __restrict__ word_enc,
                             float* __restrict__ x32,
                             unsigned short* __restrict__ x16) {
    int idx = blockIdx.x * blockDim.x + threadIdx.x;
    const int total = BS * SEQ * EMB;
    if (idx >= total) return;
    int d = idx & (EMB - 1);
    int s = (idx >> 9) % SEQ;
    int b = idx / (SEQ * EMB);
    float we = word_enc[s * EMB + d];
    float e = (s == 0) ? 0.f : w_emb[((size_t)b * NW + (s - 1)) * EMB + d];
    float v = e + we;
    x32[idx] = v;
    x16[idx] = f2bf(v);
}

// ======== dgemm: barrier-free direct GEMM for small layer GEMMs ========
// 512 thr = 8 waves; block tile 32 x 512 (wave w: cols w*64..w*64+63, rows shared).
// A,B bf16 loaded global->reg (L2-hot). MODE 0: fp32 out + bias. MODE 1: bf16 out
// + bias + relu. MODE 2: LN(out + bias + res) -> y32,y16 (full row in block).
template<int K, int MODE>
__global__ __launch_bounds__(512) void dgemm(const unsigned short* __restrict__ A,
                                             const unsigned short* __restrict__ B,
                                             const float* __restrict__ bias,
                                             const float* __restrict__ res,
                                             const float* __restrict__ g,
                                             const float* __restrict__ be,
                                             float* __restrict__ out32,
                                             unsigned short* __restrict__ out16,
                                             int M, int N) {
    int t = threadIdx.x, w = t >> 6, l = t & 63;
    int lr = l & 15, lh = l >> 4;
    int bid = blockIdx.x;
    int mt = bid % MT32, ns = bid / MT32;
    int m0 = mt * 32;
    int c0 = ns * 512 + w * 64;          // wave col base

    int ar0 = m0 + lr;       if (ar0 >= M) ar0 = M - 1;
    int ar1 = m0 + 16 + lr;  if (ar1 >= M) ar1 = M - 1;
    const unsigned short* a0 = A + (size_t)ar0 * K + lh * 8;
    const unsigned short* a1 = A + (size_t)ar1 * K + lh * 8;
    const unsigned short* bb = B + (size_t)(c0 + lr) * K + lh * 8;

    f32x4 acc[2][4] = {};
    #pragma unroll 2
    for (int k0 = 0; k0 < K; k0 += 32) {
        short8 af0 = *(const short8*)(a0 + k0);
        short8 af1 = *(const short8*)(a1 + k0);
        short8 bfv[4];
        #pragma unroll
        for (int ni = 0; ni < 4; ++ni)
            bfv[ni] = *(const short8*)(bb + (size_t)ni * 16 * K + k0);
        #pragma unroll
        for (int ni = 0; ni < 4; ++ni) {
            acc[0][ni] = __builtin_amdgcn_mfma_f32_16x16x32_bf16(af0, bfv[ni], acc[0][ni], 0, 0, 0);
            acc[1][ni] = __builtin_amdgcn_mfma_f32_16x16x32_bf16(af1, bfv[ni], acc[1][ni], 0, 0, 0);
        }
    }

    if (MODE == 2) {
        // vals = acc + bias + res; LN over full row (512 cols across 8 waves)
        __shared__ float sred[32][8], qred[32][8], mstat[32], rstat[32];
        float vals[2][4][4];
        float bv[4];
        #pragma unroll
        for (int ni = 0; ni < 4; ++ni) bv[ni] = bias[c0 + ni * 16 + lr];
        float ps[2][4] = {}, pq[2][4] = {};
        #pragma unroll
        for (int mi = 0; mi < 2; ++mi)
            #pragma unroll
            for (int r = 0; r < 4; ++r) {
                int row = m0 + mi * 16 + lh * 4 + r;
                int rc = row < M ? row : M - 1;
                #pragma unroll
                for (int ni = 0; ni < 4; ++ni) {
                    float v = acc[mi][ni][r] + bv[ni] + res[(size_t)rc * 512 + c0 + ni * 16 + lr];
                    vals[mi][ni][r] = v;
                    ps[mi][r] += v;
                    pq[mi][r] += v * v;
                }
            }
        // reduce across the 16 lanes of each lh-group
        #pragma unroll
        for (int off = 8; off >= 1; off >>= 1)
            #pragma unroll
            for (int mi = 0; mi < 2; ++mi)
                #pragma unroll
                for (int r = 0; r < 4; ++r) {
                    ps[mi][r] += __shfl_xor(ps[mi][r], off);
                    pq[mi][r] += __shfl_xor(pq[mi][r], off);
                }
        if (lr == 0) {
            #pragma unroll
            for (int mi = 0; mi < 2; ++mi)
                #pragma unroll
                for (int r = 0; r < 4; ++r) {
                    sred[mi * 16 + lh * 4 + r][w] = ps[mi][r];
                    qred[mi * 16 + lh * 4 + r][w] = pq[mi][r];
                }
        }
        __syncthreads();
        if (t < 32) {
            float S = 0.f, Q = 0.f;
            #pragma unroll
            for (int j = 0; j < 8; ++j) { S += sred[t][j]; Q += qred[t][j]; }
            float mean = S * (1.f / 512.f);
            float var  = Q * (1.f / 512.f) - mean * mean;
            mstat[t] = mean;
            rstat[t] = rsqrtf(var + 1e-5f);
        }
        __syncthreads();
        float gv[4], bev[4];
        #pragma unroll
        for (int ni = 0; ni < 4; ++ni) {
            gv[ni] = g[c0 + ni * 16 + lr];
            bev[ni] = be[c0 + ni * 16 + lr];
        }
        #pragma unroll
        for (int mi = 0; mi < 2; ++mi)
            #pragma unroll
            for (int r = 0; r < 4; ++r) {
                int lrow = mi * 16 + lh * 4 + r;
                int row = m0 + lrow;
                if (row >= M) continue;
                float mean = mstat[lrow], rstd = rstat[lrow];
                #pragma unroll
                for (int ni = 0; ni < 4; ++ni) {
                    int col = c0 + ni * 16 + lr;
                    float o = (vals[mi][ni][r] - mean) * rstd * gv[ni] + bev[ni];
                    out32[(size_t)row * 512 + col] = o;
                    out16[(size_t)row * 512 + col] = f2bf(o);
                }
            }
    } else {
        float bv[4];
        #pragma unroll
        for (int ni = 0; ni < 4; ++ni) bv[ni] = bias ? bias[c0 + ni * 16 + lr] : 0.f;
        #pragma unroll
        for (int mi = 0; mi < 2; ++mi)
            #pragma unroll
            for (int r = 0; r < 4; ++r) {
                int row = m0 + mi * 16 + lh * 4 + r;
                if (row >= M) continue;
                #pragma unroll
                for (int ni = 0; ni < 4; ++ni) {
                    int col = c0 + ni * 16 + lr;
                    float v = acc[mi][ni][r] + bv[ni];
                    if (MODE == 1) {
                        v = fmaxf(v, 0.f);
                        out16[(size_t)row * N + col] = f2bf(v);
                    } else {
                        out32[(size_t)row * N + col] = v;
                    }
                }
            }
    }
}

// ======== gemm4: logits GEMM (128x128, BK32, 3-buf depth-2, XCD swizzle) ========
template<int TM, int TN, int BK, int COMPACT>
__global__ __launch_bounds__(256) void gemm4(const unsigned short* __restrict__ A,
                                             const unsigned short* __restrict__ B,
                                             float* __restrict__ C,
                                             int M, int N, int K) {
    constexpr int LTM = ilog2c(TM);
    constexpr int LTN = ilog2c(TN);
    constexpr int FR  = TM / 32, FC = TN / 32;
    constexpr int WRH = TM / 2,  WCH = TN / 2;
    constexpr int KCH = BK / 32;
    constexpr int AI  = (TM * BK) / (8 * 256);
    constexpr int BI  = (TN * BK) / (8 * 256);
    constexpr int L   = AI + BI;
    constexpr int ASZ = TM * BK * 2;
    constexpr int STRIDE = (TM + TN) * BK * 2;
    __shared__ __align__(16) char smem[3 * STRIDE];

    int t = threadIdx.x;
    int w = t >> 6, l = t & 63;
    int wr = w >> 1, wc = w & 1;
    int lr = l & 15, lh = l >> 4;

    int mtiles = (M + TM - 1) / TM;
    int bid = blockIdx.x;
    int nchunk = gridDim.x >> 3;
    int lin = (bid & 7) * nchunk + (bid >> 3);
    int m0 = (lin % mtiles) * TM;
    int n0 = (lin / mtiles) * TN;

    f32x4 acc[FR][FC] = {};
    const int nt = K / BK;

    auto stageA = [&](int kt, int p) {
        char* dst = smem + p * STRIDE;
        #pragma unroll
        for (int i = 0; i < AI; ++i) {
            int tt = i * 256 + t;
            int row = tt & (TM - 1);
            int slot = tt >> LTM;
            int gr = m0 + row;
            if (COMPACT) gr = ((gr >> 6) * SEQ) + (gr & 63);
            else if (gr >= M) gr = M - 1;
            const unsigned short* gp = A + (size_t)gr * K + kt + slot * 8;
            __builtin_amdgcn_global_load_lds(
                (const __attribute__((address_space(1))) void*)gp,
                (__attribute__((address_space(3))) void*)(dst + (size_t)(i * 256 + w * 64) * 16),
                16, 0, 0);
        }
    };
    auto stageB = [&](int kt, int p) {
        char* dst = smem + p * STRIDE + ASZ;
        #pragma unroll
        for (int i = 0; i < BI; ++i) {
            int tt = i * 256 + t;
            int row = tt & (TN - 1);
            int slot = tt >> LTN;
            int gr = n0 + row;
            if (gr >= N) gr = N - 1;
            const unsigned short* gp = B + (size_t)gr * K + kt + slot * 8;
            __builtin_amdgcn_global_load_lds(
                (const __attribute__((address_space(1))) void*)gp,
                (__attribute__((address_space(3))) void*)(dst + (size_t)(i * 256 + w * 64) * 16),
                16, 0, 0);
        }
    };
    auto compute = [&](int p) {
        const unsigned short* as_ = (const unsigned short*)(smem + p * STRIDE);
        const unsigned short* bs_ = as_ + TM * BK;
        #pragma unroll
        for (int kk = 0; kk < KCH; ++kk) {
            short8 af[FR], bfv[FC];
            #pragma unroll
            for (int mi = 0; mi < FR; ++mi)
                af[mi] = *(const short8*)(as_ + ((size_t)(kk * 4 + lh) * TM + wr * WRH + mi * 16 + lr) * 8);
            #pragma unroll
            for (int ni = 0; ni < FC; ++ni)
                bfv[ni] = *(const short8*)(bs_ + ((size_t)(kk * 4 + lh) * TN + wc * WCH + ni * 16 + lr) * 8);
            #pragma unroll
            for (int mi = 0; mi < FR; ++mi)
                #pragma unroll
                for (int ni = 0; ni < FC; ++ni)
                    acc[mi][ni] = __builtin_amdgcn_mfma_f32_16x16x32_bf16(af[mi], bfv[ni], acc[mi][ni], 0, 0, 0);
        }
    };

    stageA(0, 0); stageB(0, 0);
    if (nt > 1) { stageA(BK, 1); stageB(BK, 1); }

    for (int it = 0; it < nt; ++it) {
        if (it + 1 < nt) wait_vm<L>(); else wait_vm<0>();
        __builtin_amdgcn_s_barrier();
        __builtin_amdgcn_sched_barrier(0);
        if (it + 2 < nt) {
            stageA((it + 2) * BK, (it + 2) % 3);
            stageB((it + 2) * BK, (it + 2) % 3);
        }
        __builtin_amdgcn_s_setprio(1);
        compute(it % 3);
        __builtin_amdgcn_s_setprio(0);
        __builtin_amdgcn_sched_barrier(0);
    }

    // coalesced fp32 epilogue via LDS transpose
    __syncthreads();
    constexpr int PAD = WCH + 4;
    constexpr int CPR = WCH / 4;
    constexpr int J   = (16 * CPR) / 64;
    float* ep = (float*)smem + (size_t)w * 16 * PAD;
    #pragma unroll
    for (int mi = 0; mi < FR; ++mi) {
        asm volatile("s_waitcnt lgkmcnt(0)" ::: "memory");
        __builtin_amdgcn_sched_barrier(0);
        #pragma unroll
        for (int ni = 0; ni < FC; ++ni)
            #pragma unroll
            for (int r = 0; r < 4; ++r)
                ep[(lh * 4 + r) * PAD + ni * 16 + lr] = acc[mi][ni][r];
        asm volatile("s_waitcnt lgkmcnt(0)" ::: "memory");
        __builtin_amdgcn_sched_barrier(0);
        #pragma unroll
        for (int j = 0; j < J; ++j) {
            int f4  = j * 64 + l;
            int row = f4 / CPR;
            int c4  = f4 % CPR;
            int grow = m0 + wr * WRH + mi * 16 + row;
            int gc   = n0 + wc * WCH + c4 * 4;
            if (grow < M) {
                float4 v = *(const float4*)(ep + row * PAD + c4 * 4);
                if (gc + 3 < N) {
                    *(float4*)(C + (size_t)grow * N + gc) = v;
                } else {
                    const float* pv = (const float*)&v;
                    #pragma unroll
                    for (int e = 0; e < 4; ++e)
                        if (gc + e < N) C[(size_t)grow * N + gc + e] = pv[e];
                }
            }
        }
    }
}

// ======== gemm2 (fallback: B fp32 inline-converted, 2-buffer) ========
template<int TM, int TN, int OUT_BF16, int RELU, int COMPACT>
__global__ __launch_bounds__(256) void gemm2(const unsigned short* __restrict__ A,
                                             const float* __restrict__ B,
                                             const float* __restrict__ bias,
                                             void* __restrict__ C,
                                             int M, int N, int K) {
    constexpr int LTM = (TM == 128) ? 7 : 6;
    constexpr int FR  = TM / 32, FC = TN / 32;
    constexpr int WRH = TM / 2,  WCH = TN / 2;
    constexpr int AI  = TM / 64;
    constexpr int TPR = 256 / TN;
    constexpr int SPT = 4 / TPR;
    constexpr int STRIDE = (TM + TN) * 64;
    __shared__ __align__(16) char smem[2 * STRIDE];

    int t = threadIdx.x;
    int w = t >> 6, l = t & 63;
    int wr = w >> 1, wc = w & 1;
    int lr = l & 15, lh = l >> 4;
    int m0 = blockIdx.y * TM, n0 = blockIdx.x * TN;

    int br = t / TPR, bh = t % TPR;
    int gbr = n0 + br; if (gbr >= N) gbr = N - 1;
    const float* bbase = B + (size_t)gbr * K + bh * (SPT * 8);

    f32x4  acc[FR][FC] = {};
    float4 breg[TN / 32];
    const int nt = K >> 5;

    auto stageA = [&](int kt, int p) {
        char* dst = smem + p * STRIDE;
        #pragma unroll
        for (int i = 0; i < AI; ++i) {
            int tt   = i * 256 + t;
            int row  = tt & (TM - 1);
            int slot = tt >> LTM;
            int gr   = m0 + row;
            if (COMPACT) gr = ((gr >> 6) * SEQ) + (gr & 63);
            else if (gr >= M) gr = M - 1;
            const unsigned short* gp = A + (size_t)gr * K + kt + slot * 8;
            __builtin_amdgcn_global_load_lds(
                (const __attribute__((address_space(1))) void*)gp,
                (__attribute__((address_space(3))) void*)(dst + (size_t)(i * 256 + w * 64) * 16),
                16, 0, 0);
        }
    };
    auto loadB = [&](int kt) {
        const float* bp = bbase + kt;
        #pragma unroll
        for (int j = 0; j < TN / 32; ++j) breg[j] = *(const float4*)(bp + j * 4);
    };
    auto writeB = [&](int p) {
        unsigned short* bs = (unsigned short*)(smem + p * STRIDE + TM * 64);
        #pragma unroll
        for (int s = 0; s < SPT; ++s) {
            ushort8n u;
            #pragma unroll
            for (int e = 0; e < 8; ++e) {
                float f = ((const float*)&breg[s * 2 + (e >> 2)])[e & 3];
                u[e] = f2bf(f);
            }
            int slot = bh * SPT + s;
            *(ushort8n*)(bs + ((size_t)slot * TN + br) * 8) = u;
        }
    };
    auto compute = [&](int p) {
        const unsigned short* as_ = (const unsigned short*)(smem + p * STRIDE);
        const unsigned short* bs_ = as_ + TM * 32;
        short8 af[FR], bfv[FC];
        #pragma unroll
        for (int mi = 0; mi < FR; ++mi)
            af[mi] = *(const short8*)(as_ + ((size_t)lh * TM + wr * WRH + mi * 16 + lr) * 8);
        #pragma unroll
        for (int ni = 0; ni < FC; ++ni)
            bfv[ni] = *(const short8*)(bs_ + ((size_t)lh * TN + wc * WCH + ni * 16 + lr) * 8);
        #pragma unroll
        for (int mi = 0; mi < FR; ++mi)
            #pragma unroll
            for (int ni = 0; ni < FC; ++ni)
                acc[mi][ni] = __builtin_amdgcn_mfma_f32_16x16x32_bf16(af[mi], bfv[ni], acc[mi][ni], 0, 0, 0);
    };

    stageA(0, 0); loadB(0); writeB(0);
    __syncthreads();
    for (int it = 0; it < nt; ++it) {
        int p = it & 1;
        if (it + 1 < nt) { stageA((it + 1) << 5, 1 - p); loadB((it + 1) << 5); }
        compute(p);
        if (it + 1 < nt) writeB(1 - p);
        __syncthreads();
    }

    #pragma unroll
    for (int ni = 0; ni < FC; ++ni) {
        int gcol = n0 + wc * WCH + ni * 16 + lr;
        if (gcol >= N) continue;
        float bv = bias ? bias[gcol] : 0.f;
        #pragma unroll
        for (int mi = 0; mi < FR; ++mi)
            #pragma unroll
            for (int r = 0; r < 4; ++r) {
                int grow = m0 + wr * WRH + mi * 16 + lh * 4 + r;
                if (grow >= M) continue;
                float v = acc[mi][ni][r] + bv;
                if (RELU) v = fmaxf(v, 0.f);
                if (OUT_BF16) ((unsigned short*)C)[(size_t)grow * N + gcol] = f2bf(v);
                else          ((float*)C)[(size_t)grow * N + gcol] = v;
            }
    }
}

// ======== fused attention: block = (qhalf, h, b), 256 threads ========
#define APAD 65
__global__ __launch_bounds__(256) void attn_fused(const float* __restrict__ qkv,
                                                  unsigned short* __restrict__ ctx16) {
    int qpart = blockIdx.x;
    int h = blockIdx.y, b = blockIdx.z;
    __shared__ float Ks[SEQ * APAD];
    __shared__ float Vs[SEQ * APAD];
    __shared__ float qsh[4][64];
    __shared__ float pws[4][SEQ + 3];

    const float* base = qkv + (size_t)b * SEQ * (3 * EMB) + h * DH;
    int t = threadIdx.x;
    for (int idx = t; idx < SEQ * 16; idx += 256) {
        int r = idx >> 4, c4 = (idx & 15) << 2;
        const float* rp = base + (size_t)r * (3 * EMB);
        float4 kv = *(const float4*)(rp + EMB + c4);
        float4 vv = *(const float4*)(rp + 2 * EMB + c4);
        float* kd = Ks + r * APAD + c4;
        kd[0] = kv.x; kd[1] = kv.y; kd[2] = kv.z; kd[3] = kv.w;
        float* vd = Vs + r * APAD + c4;
        vd[0] = vv.x; vd[1] = vv.y; vd[2] = vv.z; vd[3] = vv.w;
    }
    __syncthreads();

    int w = t >> 6, l = t & 63;
    int qstart = qpart ? 33 : 0;
    int qend   = qpart ? SEQ : 33;
    for (int qi = qstart + w; qi < qend; qi += 4) {
        qsh[w][l] = base[(size_t)qi * (3 * EMB) + l];
        float s = 0.f;
        #pragma unroll 16
        for (int d = 0; d < DH; ++d) s += qsh[w][d] * Ks[l * APAD + d];
        s *= 0.125f;
        float s64 = -1e30f;
        if (l == 0) {
            float acc64 = 0.f;
            #pragma unroll 16
            for (int d = 0; d < DH; ++d) acc64 += qsh[w][d] * Ks[64 * APAD + d];
            s64 = acc64 * 0.125f;
        }
        float m = (l == 0) ? fmaxf(s, s64) : s;
        #pragma unroll
        for (int off = 32; off >= 1; off >>= 1) m = fmaxf(m, __shfl_xor(m, off));
        float e = __expf(s - m);
        pws[w][l] = e;
        float esum = e;
        if (l == 0) { float e64 = __expf(s64 - m); pws[w][64] = e64; esum += e64; }
        #pragma unroll
        for (int off = 32; off >= 1; off >>= 1) esum += __shfl_xor(esum, off);
        float inv = 1.f / esum;
        float acc = 0.f;
        #pragma unroll 13
        for (int j = 0; j < SEQ; ++j) acc += pws[w][j] * Vs[j * APAD + l];
        ctx16[((size_t)b * SEQ + qi) * EMB + h * DH + l] = f2bf(acc * inv);
    }
}

// ---------------- layernorm of (x + p)  (fallback path only)
__global__ __launch_bounds__(128) void ln_kernel(const float* __restrict__ x,
                                                 const float* __restrict__ p,
                                                 const float* __restrict__ g,
                                                 const float* __restrict__ be,
                                                 float* __restrict__ y32,
                                                 unsigned short* __restrict__ y16) {
    int row = blockIdx.x;
    int t = threadIdx.x;
    const float4 xv = ((const float4*)(x + (size_t)row * EMB))[t];
    const float4 pv = ((const float4*)(p + (size_t)row * EMB))[t];
    float v0 = xv.x + pv.x, v1 = xv.y + pv.y, v2 = xv.z + pv.z, v3 = xv.w + pv.w;
    float sum = v0 + v1 + v2 + v3;
    float sq  = v0 * v0 + v1 * v1 + v2 * v2 + v3 * v3;
    #pragma unroll
    for (int off = 32; off >= 1; off >>= 1) {
        sum += __shfl_down(sum, off);
        sq  += __shfl_down(sq,  off);
    }
    __shared__ float s0[2], s1[2];
    if ((t & 63) == 0) { s0[t >> 6] = sum; s1[t >> 6] = sq; }
    __syncthreads();
    float S = s0[0] + s0[1], Q = s1[0] + s1[1];
    float mean = S * (1.f / EMB);
    float var  = Q * (1.f / EMB) - mean * mean;
    float rstd = rsqrtf(var + 1e-5f);
    const float4 gv = ((const float4*)g)[t];
    const float4 bv = ((const float4*)be)[t];
    float4 o;
    o.x = (v0 - mean) * rstd * gv.x + bv.x;
    o.y = (v1 - mean) * rstd * gv.y + bv.y;
    o.z = (v2 - mean) * rstd * gv.z + bv.z;
    o.w = (v3 - mean) * rstd * gv.w + bv.w;
    ((float4*)(y32 + (size_t)row * EMB))[t] = o;
    ushort4 h;
    h.x = f2bf(o.x); h.y = f2bf(o.y); h.z = f2bf(o.z); h.w = f2bf(o.w);
    ((ushort4*)(y16 + (size_t)row * EMB))[t] = h;
}

extern "C" void kernel_launch(void* const* d_in, const int* in_sizes, int n_in,
                              void* d_out, int out_size, void* d_ws, size_t ws_size,
                              hipStream_t stream) {
    const float* w_emb    = (const float*)d_in[0];
    const float* table    = (const float*)d_in[1];
    const float* word_enc = (const float*)d_in[2];
    const float* Wqkv     = (const float*)d_in[3];
    const float* bqkv     = (const float*)d_in[4];
    const float* Wo       = (const float*)d_in[5];
    const float* bo       = (const float*)d_in[6];
    const float* W1       = (const float*)d_in[7];
    const float* b1       = (const float*)d_in[8];
    const float* W2       = (const float*)d_in[9];
    const float* b2       = (const float*)d_in[10];
    const float* g1       = (const float*)d_in[11];
    const float* be1      = (const float*)d_in[12];
    const float* g2       = (const float*)d_in[13];
    const float* be2      = (const float*)d_in[14];
    float* out = (float*)d_out;

    const size_t act_bytes = (size_t)TOK * EMB * 4 * 3
                           + (size_t)TOK * 3 * EMB * 4
                           + (size_t)TOK * EMB * 2 * 3
                           + (size_t)TOK * FF_ * 2;
    const size_t wgt_bytes = (size_t)CVT_TOTAL * 2;
    const bool fast = ws_size >= act_bytes + wgt_bytes;

    char* ws = (char*)d_ws;
    unsigned short* wgt16 = nullptr;
    if (fast) { wgt16 = (unsigned short*)ws; ws += wgt_bytes; }
    float* xa32  = (float*)ws;                    ws += (size_t)TOK * EMB * 4;
    float* xb32  = (float*)ws;                    ws += (size_t)TOK * EMB * 4;
    float* qkv32 = (float*)ws;                    ws += (size_t)TOK * 3 * EMB * 4;
    float* proj32= (float*)ws;                    ws += (size_t)TOK * EMB * 4;
    unsigned short* hbuf16= (unsigned short*)ws;  ws += (size_t)TOK * FF_ * 2;
    unsigned short* xa16  = (unsigned short*)ws;  ws += (size_t)TOK * EMB * 2;
    unsigned short* xb16  = (unsigned short*)ws;  ws += (size_t)TOK * EMB * 2;
    unsigned short* ctx16 = (unsigned short*)ws;  ws += (size_t)TOK * EMB * 2;

    if (fast) cvt_kernel<<<2048, 256, 0, stream>>>(Wqkv, Wo, W1, W2, table, wgt16);

    {
        int total = BS * SEQ * EMB;
        embed_kernel<<<(total + 255) / 256, 256, 0, stream>>>(w_emb, word_enc, xa32, xa16);
    }

    if (fast) {
        const unsigned short* wq16 = wgt16;
        const unsigned short* wo16 = wgt16 + O_WO;
        const unsigned short* w116 = wgt16 + O_W1;
        const unsigned short* w216 = wgt16 + O_W2;
        const unsigned short* tab16= wgt16 + O_TAB;

        for (int l = 0; l < NL; ++l) {
            // qkv = xa @ Wqkv^T + b (fp32) : direct, 99 blocks
            dgemm<EMB,0><<<dim3(MT32 * 3), 512, 0, stream>>>(
                xa16, wq16 + (size_t)l * 3 * EMB * EMB, bqkv + (size_t)l * 3 * EMB,
                nullptr, nullptr, nullptr, qkv32, nullptr, TOK, 3 * EMB);
            attn_fused<<<dim3(2, NH, BS), 256, 0, stream>>>(qkv32, ctx16);
            // xb = LN(xa + ctx @ Wo^T + bo) : direct + fused LN, 33 blocks
            dgemm<EMB,2><<<dim3(MT32), 512, 0, stream>>>(
                ctx16, wo16 + (size_t)l * EMB * EMB, bo + (size_t)l * EMB,
                xa32, g1 + (size_t)l * EMB, be1 + (size_t)l * EMB,
                xb32, xb16, TOK, EMB);
            // h = relu(xb @ W1^T + b1) (bf16) : direct, 132 blocks
            dgemm<EMB,1><<<dim3(MT32 * 4), 512, 0, stream>>>(
                xb16, w116 + (size_t)l * FF_ * EMB, b1 + (size_t)l * FF_,
                nullptr, nullptr, nullptr, nullptr, hbuf16, TOK, FF_);
            // xa = LN(xb + h @ W2^T + b2) : direct + fused LN, 33 blocks
            dgemm<FF_,2><<<dim3(MT32), 512, 0, stream>>>(
                hbuf16, w216 + (size_t)l * EMB * FF_, b2 + (size_t)l * EMB,
                xb32, g2 + (size_t)l * EMB, be2 + (size_t)l * EMB,
                xa32, xa16, TOK, EMB);
        }
        // logits: 128x128 BK32, 3144 blocks (8 M-tiles x 393 N-tiles), COMPACT remap
        gemm4<128,128,32,1><<<dim3(3144), 256, 0, stream>>>(
            xa16, tab16, out, TOUT, VOCAB, EMB);
    } else {
        for (int l = 0; l < NL; ++l) {
            const float* Wqkv_l = Wqkv + (size_t)l * 3 * EMB * EMB;
            const float* Wo_l   = Wo   + (size_t)l * EMB * EMB;
            const float* W1_l   = W1   + (size_t)l * FF_ * EMB;
            const float* W2_l   = W2   + (size_t)l * EMB * FF_;
            gemm2<64,64,0,0,0><<<dim3((3 * EMB) / 64, (TOK + 63) / 64), 256, 0, stream>>>(
                xa16, Wqkv_l, bqkv + (size_t)l * 3 * EMB, qkv32, TOK, 3 * EMB, EMB);
            attn_fused<<<dim3(2, NH, BS), 256, 0, stream>>>(qkv32, ctx16);
            gemm2<64,64,0,0,0><<<dim3(EMB / 64, (TOK + 63) / 64), 256, 0, stream>>>(
                ctx16, Wo_l, bo + (size_t)l * EMB, proj32, TOK, EMB, EMB);
            ln_kernel<<<TOK, 128, 0, stream>>>(xa32, proj32, g1 + (size_t)l * EMB, be1 + (size_t)l * EMB, xb32, xb16);
            gemm2<64,64,1,1,0><<<dim3(FF_ / 64, (TOK + 63) / 64), 256, 0, stream>>>(
                xb16, W1_l, b1 + (size_t)l * FF_, hbuf16, TOK, FF_, EMB);
            gemm2<64,64,0,0,0><<<dim3(EMB / 64, (TOK + 63) / 64), 256, 0, stream>>>(
                hbuf16, W2_l, b2 + (size_t)l * EMB, proj32, TOK, EMB, FF_);
            ln_kernel<<<TOK, 128, 0, stream>>>(xb32, proj32, g2 + (size_t)l * EMB, be2 + (size_t)l * EMB, xa32, xa16);
        }
        gemm2<128,128,0,0,1><<<dim3((VOCAB + 127) / 128, TOUT / 128), 256, 0, stream>>>(
            xa16, table, nullptr, out, TOUT, VOCAB, EMB);
    }
}

// Round 10
// 514.852 us; speedup vs baseline: 1.7919x; 1.7919x over previous
//
#include <hip/hip_runtime.h>
#include <hip/hip_bf16.h>

// Model dims
#define EMB 512
#define NW  64
#define SEQ 65            // NW+1
#define NH  8
#define DH  64
#define NL  4
#define FF_ 2048
#define VOCAB 50257
#define BS  16
#define TOK (BS*SEQ)      // 1040
#define TOUT (BS*NW)      // 1024

typedef short short8  __attribute__((ext_vector_type(8)));   // 8 bf16 (A/B frag)
typedef unsigned short ushort8n __attribute__((ext_vector_type(8)));
typedef float f32x4   __attribute__((ext_vector_type(4)));   // C/D frag

__device__ __forceinline__ unsigned short f2bf(float f) {
    unsigned u = __float_as_uint(f);
    return (unsigned short)((u + 0x7FFF + ((u >> 16) & 1)) >> 16);  // RNE
}

template<int N> __device__ __forceinline__ void wait_vm() {
    asm volatile("s_waitcnt vmcnt(%0)" :: "n"(N) : "memory");
}

constexpr int ilog2c(int v) { return v == 32 ? 5 : v == 64 ? 6 : v == 128 ? 7 : 0; }

// ======== weight/table fp32 -> bf16 conversion ========
#define SZ_WQKV (NL*3*EMB*EMB)
#define SZ_WO   (NL*EMB*EMB)
#define SZ_W1   (NL*FF_*EMB)
#define SZ_W2   (NL*EMB*FF_)
#define SZ_TAB  (VOCAB*EMB)
#define CVT_TOTAL (SZ_WQKV+SZ_WO+SZ_W1+SZ_W2+SZ_TAB)
#define O_WO   (SZ_WQKV)
#define O_W1   (O_WO+SZ_WO)
#define O_W2   (O_W1+SZ_W1)
#define O_TAB  (O_W2+SZ_W2)

__global__ void cvt_kernel(const float* __restrict__ wqkv, const float* __restrict__ wo,
                           const float* __restrict__ w1, const float* __restrict__ w2,
                           const float* __restrict__ table, unsigned short* __restrict__ dst) {
    const int U = CVT_TOTAL / 8;
    for (int u = blockIdx.x * blockDim.x + threadIdx.x; u < U; u += gridDim.x * blockDim.x) {
        size_t elem = (size_t)u * 8;
        const float* src; size_t loc = elem;
        if      (elem < O_WO)  { src = wqkv; }
        else if (elem < O_W1)  { src = wo;    loc = elem - O_WO; }
        else if (elem < O_W2)  { src = w1;    loc = elem - O_W1; }
        else if (elem < O_TAB) { src = w2;    loc = elem - O_W2; }
        else                   { src = table; loc = elem - O_TAB; }
        float4 f0 = *(const float4*)(src + loc);
        float4 f1 = *(const float4*)(src + loc + 4);
        ushort8n o;
        o[0]=f2bf(f0.x); o[1]=f2bf(f0.y); o[2]=f2bf(f0.z); o[3]=f2bf(f0.w);
        o[4]=f2bf(f1.x); o[5]=f2bf(f1.y); o[6]=f2bf(f1.z); o[7]=f2bf(f1.w);
        *(ushort8n*)(dst + elem) = o;
    }
}

// ---------------- embed
__global__ void embed_kernel(const float* __restrict__ w_emb,
                             const float* __restrict__ word_enc,
                             float* __restrict__ x32,
                             unsigned short* __restrict__ x16) {
    int idx = blockIdx.x * blockDim.x + threadIdx.x;
    const int total = BS * SEQ * EMB;
    if (idx >= total) return;
    int d = idx & (EMB - 1);
    int s = (idx >> 9) % SEQ;
    int b = idx / (SEQ * EMB);
    float we = word_enc[s * EMB + d];
    float e = (s == 0) ? 0.f : w_emb[((size_t)b * NW + (s - 1)) * EMB + d];
    float v = e + we;
    x32[idx] = v;
    x16[idx] = f2bf(v);
}

// ======== gemm4: C = A[M,K]bf16 * B[N,K]bf16^T (+bias, +res) ========
// k-slot-major LDS, 3-buffer depth-2, SINGLE barrier per K-iter, counted vmcnt,
// setprio around MFMA. 1D grid, XCD-chunked bijective swizzle (grid % 8 == 0).
// SPLITK=2: grid covers 2 K-halves; part p writes Cp; bias/res only part 0.
template<int TM, int TN, int BK, int OUT_BF16, int RELU, int COMPACT, int SPLITK>
__global__ __launch_bounds__(256) void gemm4(const unsigned short* __restrict__ A,
                                             const unsigned short* __restrict__ B,
                                             const float* __restrict__ bias,
                                             void* __restrict__ C0,
                                             void* __restrict__ C1,
                                             const float* __restrict__ res,
                                             int M, int N, int K, int lda, int ldb) {
    constexpr int LTM = ilog2c(TM);
    constexpr int LTN = ilog2c(TN);
    constexpr int FR  = TM / 32, FC = TN / 32;
    constexpr int WRH = TM / 2,  WCH = TN / 2;
    constexpr int KCH = BK / 32;
    constexpr int AI  = (TM * BK) / (8 * 256);
    constexpr int BI  = (TN * BK) / (8 * 256);
    constexpr int L   = AI + BI;
    constexpr int ASZ = TM * BK * 2;
    constexpr int STRIDE = (TM + TN) * BK * 2;
    __shared__ __align__(16) char smem[3 * STRIDE];

    int t = threadIdx.x;
    int w = t >> 6, l = t & 63;
    int wr = w >> 1, wc = w & 1;
    int lr = l & 15, lh = l >> 4;

    // XCD-chunked bijective swizzle (grid % 8 == 0)
    int mtiles = (M + TM - 1) / TM;
    int ntiles = (N + TN - 1) / TN;
    int bid = blockIdx.x;
    int nchunk = gridDim.x >> 3;
    int lin = (bid & 7) * nchunk + (bid >> 3);
    int part = 0;
    if (SPLITK) { int tpp = mtiles * ntiles; part = (lin >= tpp); lin -= part * tpp; }
    int m0 = (lin % mtiles) * TM;
    int n0 = (lin / mtiles) * TN;

    const unsigned short* Ap = A + (size_t)part * K;
    const unsigned short* Bp = B + (size_t)part * K;
    float* Cf = (float*)(part ? C1 : C0);
    const float* biasp = (SPLITK && part) ? nullptr : bias;
    const float* resp  = (SPLITK && part) ? nullptr : res;

    f32x4 acc[FR][FC] = {};
    const int nt = K / BK;

    auto stageA = [&](int kt, int p) {
        char* dst = smem + p * STRIDE;
        #pragma unroll
        for (int i = 0; i < AI; ++i) {
            int tt = i * 256 + t;
            int row = tt & (TM - 1);
            int slot = tt >> LTM;
            int gr = m0 + row;
            if (COMPACT) gr = ((gr >> 6) * SEQ) + (gr & 63);
            else if (gr >= M) gr = M - 1;
            const unsigned short* gp = Ap + (size_t)gr * lda + kt + slot * 8;
            __builtin_amdgcn_global_load_lds(
                (const __attribute__((address_space(1))) void*)gp,
                (__attribute__((address_space(3))) void*)(dst + (size_t)(i * 256 + w * 64) * 16),
                16, 0, 0);
        }
    };
    auto stageB = [&](int kt, int p) {
        char* dst = smem + p * STRIDE + ASZ;
        #pragma unroll
        for (int i = 0; i < BI; ++i) {
            int tt = i * 256 + t;
            int row = tt & (TN - 1);
            int slot = tt >> LTN;
            int gr = n0 + row;
            if (gr >= N) gr = N - 1;
            const unsigned short* gp = Bp + (size_t)gr * ldb + kt + slot * 8;
            __builtin_amdgcn_global_load_lds(
                (const __attribute__((address_space(1))) void*)gp,
                (__attribute__((address_space(3))) void*)(dst + (size_t)(i * 256 + w * 64) * 16),
                16, 0, 0);
        }
    };
    auto compute = [&](int p) {
        const unsigned short* as_ = (const unsigned short*)(smem + p * STRIDE);
        const unsigned short* bs_ = as_ + TM * BK;
        #pragma unroll
        for (int kk = 0; kk < KCH; ++kk) {
            short8 af[FR], bfv[FC];
            #pragma unroll
            for (int mi = 0; mi < FR; ++mi)
                af[mi] = *(const short8*)(as_ + ((size_t)(kk * 4 + lh) * TM + wr * WRH + mi * 16 + lr) * 8);
            #pragma unroll
            for (int ni = 0; ni < FC; ++ni)
                bfv[ni] = *(const short8*)(bs_ + ((size_t)(kk * 4 + lh) * TN + wc * WCH + ni * 16 + lr) * 8);
            #pragma unroll
            for (int mi = 0; mi < FR; ++mi)
                #pragma unroll
                for (int ni = 0; ni < FC; ++ni)
                    acc[mi][ni] = __builtin_amdgcn_mfma_f32_16x16x32_bf16(af[mi], bfv[ni], acc[mi][ni], 0, 0, 0);
        }
    };

    // prologue: tiles 0,1 in flight (2L per wave)
    stageA(0, 0); stageB(0, 0);
    if (nt > 1) { stageA(BK, 1); stageB(BK, 1); }

    for (int it = 0; it < nt; ++it) {
        if (it + 1 < nt) wait_vm<L>(); else wait_vm<0>();   // tile it resident
        __builtin_amdgcn_s_barrier();
        __builtin_amdgcn_sched_barrier(0);
        if (it + 2 < nt) {                                   // prefetch into freed buffer
            stageA((it + 2) * BK, (it + 2) % 3);
            stageB((it + 2) * BK, (it + 2) % 3);
        }
        __builtin_amdgcn_s_setprio(1);
        compute(it % 3);
        __builtin_amdgcn_s_setprio(0);
        __builtin_amdgcn_sched_barrier(0);
    }

    // ---- epilogue ----
    if (OUT_BF16) {
        #pragma unroll
        for (int ni = 0; ni < FC; ++ni) {
            int gcol = n0 + wc * WCH + ni * 16 + lr;
            if (gcol >= N) continue;
            float bv = biasp ? biasp[gcol] : 0.f;
            #pragma unroll
            for (int mi = 0; mi < FR; ++mi)
                #pragma unroll
                for (int r = 0; r < 4; ++r) {
                    int grow = m0 + wr * WRH + mi * 16 + lh * 4 + r;
                    if (grow >= M) continue;
                    float v = acc[mi][ni][r] + bv;
                    if (RELU) v = fmaxf(v, 0.f);
                    ((unsigned short*)C0)[(size_t)grow * N + gcol] = f2bf(v);
                }
        }
    } else {
        __syncthreads();                       // K-loop LDS reads done in all waves
        constexpr int PAD = WCH + 4;
        constexpr int CPR = WCH / 4;
        constexpr int J   = (16 * CPR) / 64;
        float* ep = (float*)smem + (size_t)w * 16 * PAD;
        #pragma unroll
        for (int mi = 0; mi < FR; ++mi) {
            asm volatile("s_waitcnt lgkmcnt(0)" ::: "memory");
            __builtin_amdgcn_sched_barrier(0);
            #pragma unroll
            for (int ni = 0; ni < FC; ++ni)
                #pragma unroll
                for (int r = 0; r < 4; ++r)
                    ep[(lh * 4 + r) * PAD + ni * 16 + lr] = acc[mi][ni][r];
            asm volatile("s_waitcnt lgkmcnt(0)" ::: "memory");
            __builtin_amdgcn_sched_barrier(0);
            #pragma unroll
            for (int j = 0; j < J; ++j) {
                int f4  = j * 64 + l;
                int row = f4 / CPR;
                int c4  = f4 % CPR;
                int grow = m0 + wr * WRH + mi * 16 + row;
                int gc   = n0 + wc * WCH + c4 * 4;
                if (grow < M) {
                    float4 v = *(const float4*)(ep + row * PAD + c4 * 4);
                    if (gc + 3 < N) {
                        if (biasp) {
                            float4 b4 = *(const float4*)(biasp + gc);
                            v.x += b4.x; v.y += b4.y; v.z += b4.z; v.w += b4.w;
                        }
                        if (resp) {
                            const float* rp = resp + (size_t)grow * N + gc;
                            v.x += rp[0]; v.y += rp[1]; v.z += rp[2]; v.w += rp[3];
                        }
                        if (RELU) {
                            v.x = fmaxf(v.x, 0.f); v.y = fmaxf(v.y, 0.f);
                            v.z = fmaxf(v.z, 0.f); v.w = fmaxf(v.w, 0.f);
                        }
                        *(float4*)(Cf + (size_t)grow * N + gc) = v;
                    } else {
                        const float* pv = (const float*)&v;
                        #pragma unroll
                        for (int e = 0; e < 4; ++e)
                            if (gc + e < N) {
                                float vv = pv[e];
                                if (biasp) vv += biasp[gc + e];
                                if (resp)  vv += resp[(size_t)grow * N + gc + e];
                                if (RELU)  vv = fmaxf(vv, 0.f);
                                Cf[(size_t)grow * N + gc + e] = vv;
                            }
                    }
                }
            }
        }
    }
}

// ======== gemm2 (fallback: B fp32 inline-converted, 2-buffer) ========
template<int TM, int TN, int OUT_BF16, int RELU, int COMPACT>
__global__ __launch_bounds__(256) void gemm2(const unsigned short* __restrict__ A,
                                             const float* __restrict__ B,
                                             const float* __restrict__ bias,
                                             void* __restrict__ C,
                                             int M, int N, int K) {
    constexpr int LTM = (TM == 128) ? 7 : 6;
    constexpr int FR  = TM / 32, FC = TN / 32;
    constexpr int WRH = TM / 2,  WCH = TN / 2;
    constexpr int AI  = TM / 64;
    constexpr int TPR = 256 / TN;
    constexpr int SPT = 4 / TPR;
    constexpr int STRIDE = (TM + TN) * 64;
    __shared__ __align__(16) char smem[2 * STRIDE];

    int t = threadIdx.x;
    int w = t >> 6, l = t & 63;
    int wr = w >> 1, wc = w & 1;
    int lr = l & 15, lh = l >> 4;
    int m0 = blockIdx.y * TM, n0 = blockIdx.x * TN;

    int br = t / TPR, bh = t % TPR;
    int gbr = n0 + br; if (gbr >= N) gbr = N - 1;
    const float* bbase = B + (size_t)gbr * K + bh * (SPT * 8);

    f32x4  acc[FR][FC] = {};
    float4 breg[TN / 32];
    const int nt = K >> 5;

    auto stageA = [&](int kt, int p) {
        char* dst = smem + p * STRIDE;
        #pragma unroll
        for (int i = 0; i < AI; ++i) {
            int tt   = i * 256 + t;
            int row  = tt & (TM - 1);
            int slot = tt >> LTM;
            int gr   = m0 + row;
            if (COMPACT) gr = ((gr >> 6) * SEQ) + (gr & 63);
            else if (gr >= M) gr = M - 1;
            const unsigned short* gp = A + (size_t)gr * K + kt + slot * 8;
            __builtin_amdgcn_global_load_lds(
                (const __attribute__((address_space(1))) void*)gp,
                (__attribute__((address_space(3))) void*)(dst + (size_t)(i * 256 + w * 64) * 16),
                16, 0, 0);
        }
    };
    auto loadB = [&](int kt) {
        const float* bp = bbase + kt;
        #pragma unroll
        for (int j = 0; j < TN / 32; ++j) breg[j] = *(const float4*)(bp + j * 4);
    };
    auto writeB = [&](int p) {
        unsigned short* bs = (unsigned short*)(smem + p * STRIDE + TM * 64);
        #pragma unroll
        for (int s = 0; s < SPT; ++s) {
            ushort8n u;
            #pragma unroll
            for (int e = 0; e < 8; ++e) {
                float f = ((const float*)&breg[s * 2 + (e >> 2)])[e & 3];
                u[e] = f2bf(f);
            }
            int slot = bh * SPT + s;
            *(ushort8n*)(bs + ((size_t)slot * TN + br) * 8) = u;
        }
    };
    auto compute = [&](int p) {
        const unsigned short* as_ = (const unsigned short*)(smem + p * STRIDE);
        const unsigned short* bs_ = as_ + TM * 32;
        short8 af[FR], bfv[FC];
        #pragma unroll
        for (int mi = 0; mi < FR; ++mi)
            af[mi] = *(const short8*)(as_ + ((size_t)lh * TM + wr * WRH + mi * 16 + lr) * 8);
        #pragma unroll
        for (int ni = 0; ni < FC; ++ni)
            bfv[ni] = *(const short8*)(bs_ + ((size_t)lh * TN + wc * WCH + ni * 16 + lr) * 8);
        #pragma unroll
        for (int mi = 0; mi < FR; ++mi)
            #pragma unroll
            for (int ni = 0; ni < FC; ++ni)
                acc[mi][ni] = __builtin_amdgcn_mfma_f32_16x16x32_bf16(af[mi], bfv[ni], acc[mi][ni], 0, 0, 0);
    };

    stageA(0, 0); loadB(0); writeB(0);
    __syncthreads();
    for (int it = 0; it < nt; ++it) {
        int p = it & 1;
        if (it + 1 < nt) { stageA((it + 1) << 5, 1 - p); loadB((it + 1) << 5); }
        compute(p);
        if (it + 1 < nt) writeB(1 - p);
        __syncthreads();
    }

    #pragma unroll
    for (int ni = 0; ni < FC; ++ni) {
        int gcol = n0 + wc * WCH + ni * 16 + lr;
        if (gcol >= N) continue;
        float bv = bias ? bias[gcol] : 0.f;
        #pragma unroll
        for (int mi = 0; mi < FR; ++mi)
            #pragma unroll
            for (int r = 0; r < 4; ++r) {
                int grow = m0 + wr * WRH + mi * 16 + lh * 4 + r;
                if (grow >= M) continue;
                float v = acc[mi][ni][r] + bv;
                if (RELU) v = fmaxf(v, 0.f);
                if (OUT_BF16) ((unsigned short*)C)[(size_t)grow * N + gcol] = f2bf(v);
                else          ((float*)C)[(size_t)grow * N + gcol] = v;
            }
    }
}

// ======== fused attention: block = (qhalf, h, b), 256 threads ========
// Stage K,V (fp32) into LDS once (stride 65 -> conflict-free both phases).
// Per wave per query: q via wave-LDS broadcast slot; lane=j scores (lane 0
// folds key 64); shfl_xor max/sum; lane=d PV from LDS.
#define APAD 65
__global__ __launch_bounds__(256) void attn_fused(const float* __restrict__ qkv,
                                                  unsigned short* __restrict__ ctx16) {
    int qpart = blockIdx.x;        // 0: q 0..32, 1: q 33..64
    int h = blockIdx.y, b = blockIdx.z;
    __shared__ float Ks[SEQ * APAD];
    __shared__ float Vs[SEQ * APAD];
    __shared__ float qsh[4][64];
    __shared__ float pws[4][SEQ + 3];

    const float* base = qkv + (size_t)b * SEQ * (3 * EMB) + h * DH;
    int t = threadIdx.x;
    for (int idx = t; idx < SEQ * 16; idx += 256) {
        int r = idx >> 4, c4 = (idx & 15) << 2;
        const float* rp = base + (size_t)r * (3 * EMB);
        float4 kv = *(const float4*)(rp + EMB + c4);
        float4 vv = *(const float4*)(rp + 2 * EMB + c4);
        float* kd = Ks + r * APAD + c4;
        kd[0] = kv.x; kd[1] = kv.y; kd[2] = kv.z; kd[3] = kv.w;
        float* vd = Vs + r * APAD + c4;
        vd[0] = vv.x; vd[1] = vv.y; vd[2] = vv.z; vd[3] = vv.w;
    }
    __syncthreads();

    int w = t >> 6, l = t & 63;
    int qstart = qpart ? 33 : 0;
    int qend   = qpart ? SEQ : 33;
    for (int qi = qstart + w; qi < qend; qi += 4) {
        qsh[w][l] = base[(size_t)qi * (3 * EMB) + l];   // wave-local; LDS in-order
        float s = 0.f;
        #pragma unroll 16
        for (int d = 0; d < DH; ++d) s += qsh[w][d] * Ks[l * APAD + d];
        s *= 0.125f;
        float s64 = -1e30f;
        if (l == 0) {
            float acc64 = 0.f;
            #pragma unroll 16
            for (int d = 0; d < DH; ++d) acc64 += qsh[w][d] * Ks[64 * APAD + d];
            s64 = acc64 * 0.125f;
        }
        float m = (l == 0) ? fmaxf(s, s64) : s;
        #pragma unroll
        for (int off = 32; off >= 1; off >>= 1) m = fmaxf(m, __shfl_xor(m, off));
        float e = __expf(s - m);
        pws[w][l] = e;
        float esum = e;
        if (l == 0) { float e64 = __expf(s64 - m); pws[w][64] = e64; esum += e64; }
        #pragma unroll
        for (int off = 32; off >= 1; off >>= 1) esum += __shfl_xor(esum, off);
        float inv = 1.f / esum;
        float acc = 0.f;
        #pragma unroll 13
        for (int j = 0; j < SEQ; ++j) acc += pws[w][j] * Vs[j * APAD + l];
        ctx16[((size_t)b * SEQ + qi) * EMB + h * DH + l] = f2bf(acc * inv);
    }
}

// ---------------- layernorm of (x + p)
__global__ __launch_bounds__(128) void ln_kernel(const float* __restrict__ x,
                                                 const float* __restrict__ p,
                                                 const float* __restrict__ g,
                                                 const float* __restrict__ be,
                                                 float* __restrict__ y32,
                                                 unsigned short* __restrict__ y16) {
    int row = blockIdx.x;
    int t = threadIdx.x;
    const float4 xv = ((const float4*)(x + (size_t)row * EMB))[t];
    const float4 pv = ((const float4*)(p + (size_t)row * EMB))[t];
    float v0 = xv.x + pv.x, v1 = xv.y + pv.y, v2 = xv.z + pv.z, v3 = xv.w + pv.w;
    float sum = v0 + v1 + v2 + v3;
    float sq  = v0 * v0 + v1 * v1 + v2 * v2 + v3 * v3;
    #pragma unroll
    for (int off = 32; off >= 1; off >>= 1) {
        sum += __shfl_down(sum, off);
        sq  += __shfl_down(sq,  off);
    }
    __shared__ float s0[2], s1[2];
    if ((t & 63) == 0) { s0[t >> 6] = sum; s1[t >> 6] = sq; }
    __syncthreads();
    float S = s0[0] + s0[1], Q = s1[0] + s1[1];
    float mean = S * (1.f / EMB);
    float var  = Q * (1.f / EMB) - mean * mean;
    float rstd = rsqrtf(var + 1e-5f);
    const float4 gv = ((const float4*)g)[t];
    const float4 bv = ((const float4*)be)[t];
    float4 o;
    o.x = (v0 - mean) * rstd * gv.x + bv.x;
    o.y = (v1 - mean) * rstd * gv.y + bv.y;
    o.z = (v2 - mean) * rstd * gv.z + bv.z;
    o.w = (v3 - mean) * rstd * gv.w + bv.w;
    ((float4*)(y32 + (size_t)row * EMB))[t] = o;
    ushort4 h;
    h.x = f2bf(o.x); h.y = f2bf(o.y); h.z = f2bf(o.z); h.w = f2bf(o.w);
    ((ushort4*)(y16 + (size_t)row * EMB))[t] = h;
}

extern "C" void kernel_launch(void* const* d_in, const int* in_sizes, int n_in,
                              void* d_out, int out_size, void* d_ws, size_t ws_size,
                              hipStream_t stream) {
    const float* w_emb    = (const float*)d_in[0];
    const float* table    = (const float*)d_in[1];
    const float* word_enc = (const float*)d_in[2];
    const float* Wqkv     = (const float*)d_in[3];
    const float* bqkv     = (const float*)d_in[4];
    const float* Wo       = (const float*)d_in[5];
    const float* bo       = (const float*)d_in[6];
    const float* W1       = (const float*)d_in[7];
    const float* b1       = (const float*)d_in[8];
    const float* W2       = (const float*)d_in[9];
    const float* b2       = (const float*)d_in[10];
    const float* g1       = (const float*)d_in[11];
    const float* be1      = (const float*)d_in[12];
    const float* g2       = (const float*)d_in[13];
    const float* be2      = (const float*)d_in[14];
    float* out = (float*)d_out;

    const size_t act_bytes = (size_t)TOK * EMB * 4 * 3
                           + (size_t)TOK * 3 * EMB * 4
                           + (size_t)TOK * EMB * 2 * 3
                           + (size_t)TOK * FF_ * 2;
    const size_t wgt_bytes = (size_t)CVT_TOTAL * 2;
    const bool fast = ws_size >= act_bytes + wgt_bytes;

    char* ws = (char*)d_ws;
    unsigned short* wgt16 = nullptr;
    if (fast) { wgt16 = (unsigned short*)ws; ws += wgt_bytes; }
    float* xa32  = (float*)ws;                    ws += (size_t)TOK * EMB * 4;
    float* xb32  = (float*)ws;                    ws += (size_t)TOK * EMB * 4;
    float* qkv32 = (float*)ws;                    ws += (size_t)TOK * 3 * EMB * 4;
    float* proj32= (float*)ws;                    ws += (size_t)TOK * EMB * 4;
    unsigned short* hbuf16= (unsigned short*)ws;  ws += (size_t)TOK * FF_ * 2;
    unsigned short* xa16  = (unsigned short*)ws;  ws += (size_t)TOK * EMB * 2;
    unsigned short* xb16  = (unsigned short*)ws;  ws += (size_t)TOK * EMB * 2;
    unsigned short* ctx16 = (unsigned short*)ws;  ws += (size_t)TOK * EMB * 2;
    float* projb  = qkv32;       // Wo/ff2 split-K part1 (qkv32 dead by then)

    if (fast) cvt_kernel<<<2048, 256, 0, stream>>>(Wqkv, Wo, W1, W2, table, wgt16);

    {
        int total = BS * SEQ * EMB;
        embed_kernel<<<(total + 255) / 256, 256, 0, stream>>>(w_emb, word_enc, xa32, xa16);
    }

    if (fast) {
        const unsigned short* wq16 = wgt16;
        const unsigned short* wo16 = wgt16 + O_WO;
        const unsigned short* w116 = wgt16 + O_W1;
        const unsigned short* w216 = wgt16 + O_W2;
        const unsigned short* tab16= wgt16 + O_TAB;

        for (int l = 0; l < NL; ++l) {
            // qkv: full K=512, grid 17*24=408 (div by 8)
            gemm4<64,64,64,0,0,0,0><<<dim3(408), 256, 0, stream>>>(
                xa16, wq16 + (size_t)l * 3 * EMB * EMB, bqkv + (size_t)l * 3 * EMB,
                qkv32, nullptr, nullptr, TOK, 3 * EMB, EMB, EMB, EMB);
            attn_fused<<<dim3(2, NH, BS), 256, 0, stream>>>(qkv32, ctx16);
            // Wo: split-K2 (Kp=256); res=xa32 in part0; ln sums parts
            gemm4<64,32,64,0,0,0,1><<<dim3(544), 256, 0, stream>>>(
                ctx16, wo16 + (size_t)l * EMB * EMB, bo + (size_t)l * EMB,
                proj32, projb, xa32, TOK, EMB, 256, EMB, EMB);
            ln_kernel<<<TOK, 128, 0, stream>>>(proj32, projb,
                g1 + (size_t)l * EMB, be1 + (size_t)l * EMB, xb32, xb16);
            // ff1: full K=512, relu, bf16 out
            gemm4<64,64,64,1,1,0,0><<<dim3(544), 256, 0, stream>>>(
                xb16, w116 + (size_t)l * FF_ * EMB, b1 + (size_t)l * FF_,
                hbuf16, nullptr, nullptr, TOK, FF_, EMB, EMB, EMB);
            // ff2: split-K2 (Kp=1024); res=xb32 in part0
            gemm4<64,32,64,0,0,0,1><<<dim3(544), 256, 0, stream>>>(
                hbuf16, w216 + (size_t)l * EMB * FF_, b2 + (size_t)l * EMB,
                proj32, projb, xb32, TOK, EMB, 1024, FF_, FF_);
            ln_kernel<<<TOK, 128, 0, stream>>>(proj32, projb,
                g2 + (size_t)l * EMB, be2 + (size_t)l * EMB, xa32, xa16);
        }
        // logits: 3144 blocks (8 M-tiles x 393 N-tiles), COMPACT row remap
        gemm4<128,128,32,0,0,1,0><<<dim3(3144), 256, 0, stream>>>(
            xa16, tab16, nullptr, out, nullptr, nullptr, TOUT, VOCAB, EMB, EMB, EMB);
    } else {
        for (int l = 0; l < NL; ++l) {
            const float* Wqkv_l = Wqkv + (size_t)l * 3 * EMB * EMB;
            const float* Wo_l   = Wo   + (size_t)l * EMB * EMB;
            const float* W1_l   = W1   + (size_t)l * FF_ * EMB;
            const float* W2_l   = W2   + (size_t)l * EMB * FF_;
            gemm2<64,64,0,0,0><<<dim3((3 * EMB) / 64, (TOK + 63) / 64), 256, 0, stream>>>(
                xa16, Wqkv_l, bqkv + (size_t)l * 3 * EMB, qkv32, TOK, 3 * EMB, EMB);
            attn_fused<<<dim3(2, NH, BS), 256, 0, stream>>>(qkv32, ctx16);
            gemm2<64,64,0,0,0><<<dim3(EMB / 64, (TOK + 63) / 64), 256, 0, stream>>>(
                ctx16, Wo_l, bo + (size_t)l * EMB, proj32, TOK, EMB, EMB);
            ln_kernel<<<TOK, 128, 0, stream>>>(xa32, proj32, g1 + (size_t)l * EMB, be1 + (size_t)l * EMB, xb32, xb16);
            gemm2<64,64,1,1,0><<<dim3(FF_ / 64, (TOK + 63) / 64), 256, 0, stream>>>(
                xb16, W1_l, b1 + (size_t)l * FF_, hbuf16, TOK, FF_, EMB);
            gemm2<64,64,0,0,0><<<dim3(EMB / 64, (TOK + 63) / 64), 256, 0, stream>>>(
                hbuf16, W2_l, b2 + (size_t)l * EMB, proj32, TOK, EMB, FF_);
            ln_kernel<<<TOK, 128, 0, stream>>>(xb32, proj32, g2 + (size_t)l * EMB, be2 + (size_t)l * EMB, xa32, xa16);
        }
        gemm2<128,128,0,0,1><<<dim3((VOCAB + 127) / 128, TOUT / 128), 256, 0, stream>>>(
            xa16, table, nullptr, out, TOUT, VOCAB, EMB);
    }
}

// Round 11
// 510.818 us; speedup vs baseline: 1.8061x; 1.0079x over previous
//
#include <hip/hip_runtime.h>
#include <hip/hip_bf16.h>

// Model dims
#define EMB 512
#define NW  64
#define SEQ 65            // NW+1
#define NH  8
#define DH  64
#define NL  4
#define FF_ 2048
#define VOCAB 50257
#define BS  16
#define TOK (BS*SEQ)      // 1040
#define TOUT (BS*NW)      // 1024

typedef short short8  __attribute__((ext_vector_type(8)));   // 8 bf16 (A/B frag)
typedef unsigned short ushort8n __attribute__((ext_vector_type(8)));
typedef float f32x4   __attribute__((ext_vector_type(4)));   // C/D frag

__device__ __forceinline__ unsigned short f2bf(float f) {
    unsigned u = __float_as_uint(f);
    return (unsigned short)((u + 0x7FFF + ((u >> 16) & 1)) >> 16);  // RNE
}

template<int N> __device__ __forceinline__ void wait_vm() {
    asm volatile("s_waitcnt vmcnt(%0)" :: "n"(N) : "memory");
}

constexpr int ilog2c(int v) { return v == 32 ? 5 : v == 64 ? 6 : v == 128 ? 7 : 0; }

// ======== weight/table fp32 -> bf16 conversion ========
#define SZ_WQKV (NL*3*EMB*EMB)
#define SZ_WO   (NL*EMB*EMB)
#define SZ_W1   (NL*FF_*EMB)
#define SZ_W2   (NL*EMB*FF_)
#define SZ_TAB  (VOCAB*EMB)
#define CVT_TOTAL (SZ_WQKV+SZ_WO+SZ_W1+SZ_W2+SZ_TAB)
#define O_WO   (SZ_WQKV)
#define O_W1   (O_WO+SZ_WO)
#define O_W2   (O_W1+SZ_W1)
#define O_TAB  (O_W2+SZ_W2)

__global__ void cvt_kernel(const float* __restrict__ wqkv, const float* __restrict__ wo,
                           const float* __restrict__ w1, const float* __restrict__ w2,
                           const float* __restrict__ table, unsigned short* __restrict__ dst) {
    const int U = CVT_TOTAL / 8;
    for (int u = blockIdx.x * blockDim.x + threadIdx.x; u < U; u += gridDim.x * blockDim.x) {
        size_t elem = (size_t)u * 8;
        const float* src; size_t loc = elem;
        if      (elem < O_WO)  { src = wqkv; }
        else if (elem < O_W1)  { src = wo;    loc = elem - O_WO; }
        else if (elem < O_W2)  { src = w1;    loc = elem - O_W1; }
        else if (elem < O_TAB) { src = w2;    loc = elem - O_W2; }
        else                   { src = table; loc = elem - O_TAB; }
        float4 f0 = *(const float4*)(src + loc);
        float4 f1 = *(const float4*)(src + loc + 4);
        ushort8n o;
        o[0]=f2bf(f0.x); o[1]=f2bf(f0.y); o[2]=f2bf(f0.z); o[3]=f2bf(f0.w);
        o[4]=f2bf(f1.x); o[5]=f2bf(f1.y); o[6]=f2bf(f1.z); o[7]=f2bf(f1.w);
        *(ushort8n*)(dst + elem) = o;
    }
}

// ---------------- embed
__global__ void embed_kernel(const float* __restrict__ w_emb,
                             const float* __restrict__ word_enc,
                             float* __restrict__ x32,
                             unsigned short* __restrict__ x16) {
    int idx = blockIdx.x * blockDim.x + threadIdx.x;
    const int total = BS * SEQ * EMB;
    if (idx >= total) return;
    int d = idx & (EMB - 1);
    int s = (idx >> 9) % SEQ;
    int b = idx / (SEQ * EMB);
    float we = word_enc[s * EMB + d];
    float e = (s == 0) ? 0.f : w_emb[((size_t)b * NW + (s - 1)) * EMB + d];
    float v = e + we;
    x32[idx] = v;
    x16[idx] = f2bf(v);
}

// ======== gemm4: layer GEMMs (unchanged from best-known config) ========
template<int TM, int TN, int BK, int OUT_BF16, int RELU, int COMPACT, int SPLITK>
__global__ __launch_bounds__(256) void gemm4(const unsigned short* __restrict__ A,
                                             const unsigned short* __restrict__ B,
                                             const float* __restrict__ bias,
                                             void* __restrict__ C0,
                                             void* __restrict__ C1,
                                             const float* __restrict__ res,
                                             int M, int N, int K, int lda, int ldb) {
    constexpr int LTM = ilog2c(TM);
    constexpr int LTN = ilog2c(TN);
    constexpr int FR  = TM / 32, FC = TN / 32;
    constexpr int WRH = TM / 2,  WCH = TN / 2;
    constexpr int KCH = BK / 32;
    constexpr int AI  = (TM * BK) / (8 * 256);
    constexpr int BI  = (TN * BK) / (8 * 256);
    constexpr int L   = AI + BI;
    constexpr int ASZ = TM * BK * 2;
    constexpr int STRIDE = (TM + TN) * BK * 2;
    __shared__ __align__(16) char smem[3 * STRIDE];

    int t = threadIdx.x;
    int w = t >> 6, l = t & 63;
    int wr = w >> 1, wc = w & 1;
    int lr = l & 15, lh = l >> 4;

    int mtiles = (M + TM - 1) / TM;
    int ntiles = (N + TN - 1) / TN;
    int bid = blockIdx.x;
    int nchunk = gridDim.x >> 3;
    int lin = (bid & 7) * nchunk + (bid >> 3);
    int part = 0;
    if (SPLITK) { int tpp = mtiles * ntiles; part = (lin >= tpp); lin -= part * tpp; }
    int m0 = (lin % mtiles) * TM;
    int n0 = (lin / mtiles) * TN;

    const unsigned short* Ap = A + (size_t)part * K;
    const unsigned short* Bp = B + (size_t)part * K;
    float* Cf = (float*)(part ? C1 : C0);
    const float* biasp = (SPLITK && part) ? nullptr : bias;
    const float* resp  = (SPLITK && part) ? nullptr : res;

    f32x4 acc[FR][FC] = {};
    const int nt = K / BK;

    auto stageA = [&](int kt, int p) {
        char* dst = smem + p * STRIDE;
        #pragma unroll
        for (int i = 0; i < AI; ++i) {
            int tt = i * 256 + t;
            int row = tt & (TM - 1);
            int slot = tt >> LTM;
            int gr = m0 + row;
            if (COMPACT) gr = ((gr >> 6) * SEQ) + (gr & 63);
            else if (gr >= M) gr = M - 1;
            const unsigned short* gp = Ap + (size_t)gr * lda + kt + slot * 8;
            __builtin_amdgcn_global_load_lds(
                (const __attribute__((address_space(1))) void*)gp,
                (__attribute__((address_space(3))) void*)(dst + (size_t)(i * 256 + w * 64) * 16),
                16, 0, 0);
        }
    };
    auto stageB = [&](int kt, int p) {
        char* dst = smem + p * STRIDE + ASZ;
        #pragma unroll
        for (int i = 0; i < BI; ++i) {
            int tt = i * 256 + t;
            int row = tt & (TN - 1);
            int slot = tt >> LTN;
            int gr = n0 + row;
            if (gr >= N) gr = N - 1;
            const unsigned short* gp = Bp + (size_t)gr * ldb + kt + slot * 8;
            __builtin_amdgcn_global_load_lds(
                (const __attribute__((address_space(1))) void*)gp,
                (__attribute__((address_space(3))) void*)(dst + (size_t)(i * 256 + w * 64) * 16),
                16, 0, 0);
        }
    };
    auto compute = [&](int p) {
        const unsigned short* as_ = (const unsigned short*)(smem + p * STRIDE);
        const unsigned short* bs_ = as_ + TM * BK;
        #pragma unroll
        for (int kk = 0; kk < KCH; ++kk) {
            short8 af[FR], bfv[FC];
            #pragma unroll
            for (int mi = 0; mi < FR; ++mi)
                af[mi] = *(const short8*)(as_ + ((size_t)(kk * 4 + lh) * TM + wr * WRH + mi * 16 + lr) * 8);
            #pragma unroll
            for (int ni = 0; ni < FC; ++ni)
                bfv[ni] = *(const short8*)(bs_ + ((size_t)(kk * 4 + lh) * TN + wc * WCH + ni * 16 + lr) * 8);
            #pragma unroll
            for (int mi = 0; mi < FR; ++mi)
                #pragma unroll
                for (int ni = 0; ni < FC; ++ni)
                    acc[mi][ni] = __builtin_amdgcn_mfma_f32_16x16x32_bf16(af[mi], bfv[ni], acc[mi][ni], 0, 0, 0);
        }
    };

    stageA(0, 0); stageB(0, 0);
    if (nt > 1) { stageA(BK, 1); stageB(BK, 1); }

    for (int it = 0; it < nt; ++it) {
        if (it + 1 < nt) wait_vm<L>(); else wait_vm<0>();
        __builtin_amdgcn_s_barrier();
        __builtin_amdgcn_sched_barrier(0);
        if (it + 2 < nt) {
            stageA((it + 2) * BK, (it + 2) % 3);
            stageB((it + 2) * BK, (it + 2) % 3);
        }
        __builtin_amdgcn_s_setprio(1);
        compute(it % 3);
        __builtin_amdgcn_s_setprio(0);
        __builtin_amdgcn_sched_barrier(0);
    }

    if (OUT_BF16) {
        #pragma unroll
        for (int ni = 0; ni < FC; ++ni) {
            int gcol = n0 + wc * WCH + ni * 16 + lr;
            if (gcol >= N) continue;
            float bv = biasp ? biasp[gcol] : 0.f;
            #pragma unroll
            for (int mi = 0; mi < FR; ++mi)
                #pragma unroll
                for (int r = 0; r < 4; ++r) {
                    int grow = m0 + wr * WRH + mi * 16 + lh * 4 + r;
                    if (grow >= M) continue;
                    float v = acc[mi][ni][r] + bv;
                    if (RELU) v = fmaxf(v, 0.f);
                    ((unsigned short*)C0)[(size_t)grow * N + gcol] = f2bf(v);
                }
        }
    } else {
        __syncthreads();
        constexpr int PAD = WCH + 4;
        constexpr int CPR = WCH / 4;
        constexpr int J   = (16 * CPR) / 64;
        float* ep = (float*)smem + (size_t)w * 16 * PAD;
        #pragma unroll
        for (int mi = 0; mi < FR; ++mi) {
            asm volatile("s_waitcnt lgkmcnt(0)" ::: "memory");
            __builtin_amdgcn_sched_barrier(0);
            #pragma unroll
            for (int ni = 0; ni < FC; ++ni)
                #pragma unroll
                for (int r = 0; r < 4; ++r)
                    ep[(lh * 4 + r) * PAD + ni * 16 + lr] = acc[mi][ni][r];
            asm volatile("s_waitcnt lgkmcnt(0)" ::: "memory");
            __builtin_amdgcn_sched_barrier(0);
            #pragma unroll
            for (int j = 0; j < J; ++j) {
                int f4  = j * 64 + l;
                int row = f4 / CPR;
                int c4  = f4 % CPR;
                int grow = m0 + wr * WRH + mi * 16 + row;
                int gc   = n0 + wc * WCH + c4 * 4;
                if (grow < M) {
                    float4 v = *(const float4*)(ep + row * PAD + c4 * 4);
                    if (gc + 3 < N) {
                        if (biasp) {
                            float4 b4 = *(const float4*)(biasp + gc);
                            v.x += b4.x; v.y += b4.y; v.z += b4.z; v.w += b4.w;
                        }
                        if (resp) {
                            const float* rp = resp + (size_t)grow * N + gc;
                            v.x += rp[0]; v.y += rp[1]; v.z += rp[2]; v.w += rp[3];
                        }
                        if (RELU) {
                            v.x = fmaxf(v.x, 0.f); v.y = fmaxf(v.y, 0.f);
                            v.z = fmaxf(v.z, 0.f); v.w = fmaxf(v.w, 0.f);
                        }
                        *(float4*)(Cf + (size_t)grow * N + gc) = v;
                    } else {
                        const float* pv = (const float*)&v;
                        #pragma unroll
                        for (int e = 0; e < 4; ++e)
                            if (gc + e < N) {
                                float vv = pv[e];
                                if (biasp) vv += biasp[gc + e];
                                if (resp)  vv += resp[(size_t)grow * N + gc + e];
                                if (RELU)  vv = fmaxf(vv, 0.f);
                                Cf[(size_t)grow * N + gc + e] = vv;
                            }
                    }
                }
            }
        }
    }
}

// ======== gemm5: logits 256x256 tile, 512 thr = 8 waves (2x4), BK=32 ========
// Same proven loop: k-slot-major LDS, 3-buffer depth-2, single barrier,
// counted vmcnt, setprio. Bijective XCD-chunked swizzle (any grid size).
// COMPACT row remap for A (drop s=64 tokens). 96 KB LDS -> 1 block/CU.
__global__ __launch_bounds__(512) void gemm5(const unsigned short* __restrict__ A,
                                             const unsigned short* __restrict__ B,
                                             float* __restrict__ C,
                                             int M, int N, int K) {
    constexpr int TM = 256, TN = 256, BK = 32;
    constexpr int AI = 2, BI = 2, L = 4;
    constexpr int ASZ = TM * BK * 2;            // 16 KB
    constexpr int STRIDE = (TM + TN) * BK * 2;  // 32 KB
    __shared__ __align__(16) char smem[3 * STRIDE];   // 96 KB

    int t = threadIdx.x;
    int w = t >> 6, l = t & 63;
    int wr = w >> 2, wc = w & 3;       // 2 x 4 wave grid
    int lr = l & 15, lh = l >> 4;

    // bijective XCD-chunked swizzle (works for any gridDim)
    int nwg = gridDim.x;
    int q = nwg >> 3, r = nwg & 7;
    int bid = blockIdx.x;
    int xcd = bid & 7, i0 = bid >> 3;
    int lin = (xcd < r ? xcd * (q + 1) : r * (q + 1) + (xcd - r) * q) + i0;
    int mtiles = (M + TM - 1) / TM;    // 4
    int m0 = (lin % mtiles) * TM;
    int n0 = (lin / mtiles) * TN;

    f32x4 acc[8][4] = {};              // per wave: 128x64 output
    const int nt = K / BK;             // 16

    auto stageA = [&](int kt, int p) {
        char* dst = smem + p * STRIDE;
        #pragma unroll
        for (int i = 0; i < AI; ++i) {
            int tt = i * 512 + t;
            int row = tt & (TM - 1);
            int slot = tt >> 8;
            int gr = m0 + row;
            gr = ((gr >> 6) * SEQ) + (gr & 63);    // COMPACT remap
            const unsigned short* gp = A + (size_t)gr * K + kt + slot * 8;
            __builtin_amdgcn_global_load_lds(
                (const __attribute__((address_space(1))) void*)gp,
                (__attribute__((address_space(3))) void*)(dst + (size_t)(i * 512 + w * 64) * 16),
                16, 0, 0);
        }
    };
    auto stageB = [&](int kt, int p) {
        char* dst = smem + p * STRIDE + ASZ;
        #pragma unroll
        for (int i = 0; i < BI; ++i) {
            int tt = i * 512 + t;
            int row = tt & (TN - 1);
            int slot = tt >> 8;
            int gr = n0 + row;
            if (gr >= N) gr = N - 1;
            const unsigned short* gp = B + (size_t)gr * K + kt + slot * 8;
            __builtin_amdgcn_global_load_lds(
                (const __attribute__((address_space(1))) void*)gp,
                (__attribute__((address_space(3))) void*)(dst + (size_t)(i * 512 + w * 64) * 16),
                16, 0, 0);
        }
    };
    auto compute = [&](int p) {
        const unsigned short* as_ = (const unsigned short*)(smem + p * STRIDE);
        const unsigned short* bs_ = as_ + TM * BK;
        short8 af[8], bf[4];
        #pragma unroll
        for (int mi = 0; mi < 8; ++mi)
            af[mi] = *(const short8*)(as_ + ((size_t)lh * TM + wr * 128 + mi * 16 + lr) * 8);
        #pragma unroll
        for (int ni = 0; ni < 4; ++ni)
            bf[ni] = *(const short8*)(bs_ + ((size_t)lh * TN + wc * 64 + ni * 16 + lr) * 8);
        #pragma unroll
        for (int mi = 0; mi < 8; ++mi)
            #pragma unroll
            for (int ni = 0; ni < 4; ++ni)
                acc[mi][ni] = __builtin_amdgcn_mfma_f32_16x16x32_bf16(af[mi], bf[ni], acc[mi][ni], 0, 0, 0);
    };

    stageA(0, 0); stageB(0, 0);
    if (nt > 1) { stageA(BK, 1); stageB(BK, 1); }

    for (int it = 0; it < nt; ++it) {
        if (it + 1 < nt) wait_vm<L>(); else wait_vm<0>();
        __builtin_amdgcn_s_barrier();
        __builtin_amdgcn_sched_barrier(0);
        if (it + 2 < nt) {
            stageA((it + 2) * BK, (it + 2) % 3);
            stageB((it + 2) * BK, (it + 2) % 3);
        }
        __builtin_amdgcn_s_setprio(1);
        compute(it % 3);
        __builtin_amdgcn_s_setprio(0);
        __builtin_amdgcn_sched_barrier(0);
    }

    // coalesced fp32 epilogue via LDS transpose (per-wave region, PAD=68)
    __syncthreads();
    constexpr int PAD = 68;
    float* ep = (float*)smem + (size_t)w * 16 * PAD;
    #pragma unroll
    for (int mi = 0; mi < 8; ++mi) {
        asm volatile("s_waitcnt lgkmcnt(0)" ::: "memory");
        __builtin_amdgcn_sched_barrier(0);
        #pragma unroll
        for (int ni = 0; ni < 4; ++ni)
            #pragma unroll
            for (int rr = 0; rr < 4; ++rr)
                ep[(lh * 4 + rr) * PAD + ni * 16 + lr] = acc[mi][ni][rr];
        asm volatile("s_waitcnt lgkmcnt(0)" ::: "memory");
        __builtin_amdgcn_sched_barrier(0);
        #pragma unroll
        for (int j = 0; j < 4; ++j) {
            int f4  = j * 64 + l;
            int row = f4 >> 4;
            int c4  = f4 & 15;
            int grow = m0 + wr * 128 + mi * 16 + row;
            int gc   = n0 + wc * 64 + c4 * 4;
            if (grow < M) {
                float4 v = *(const float4*)(ep + row * PAD + c4 * 4);
                if (gc + 3 < N) {
                    *(float4*)(C + (size_t)grow * N + gc) = v;
                } else {
                    const float* pv = (const float*)&v;
                    #pragma unroll
                    for (int e = 0; e < 4; ++e)
                        if (gc + e < N) C[(size_t)grow * N + gc + e] = pv[e];
                }
            }
        }
    }
}

// ======== gemm2 (fallback: B fp32 inline-converted, 2-buffer) ========
template<int TM, int TN, int OUT_BF16, int RELU, int COMPACT>
__global__ __launch_bounds__(256) void gemm2(const unsigned short* __restrict__ A,
                                             const float* __restrict__ B,
                                             const float* __restrict__ bias,
                                             void* __restrict__ C,
                                             int M, int N, int K) {
    constexpr int LTM = (TM == 128) ? 7 : 6;
    constexpr int FR  = TM / 32, FC = TN / 32;
    constexpr int WRH = TM / 2,  WCH = TN / 2;
    constexpr int AI  = TM / 64;
    constexpr int TPR = 256 / TN;
    constexpr int SPT = 4 / TPR;
    constexpr int STRIDE = (TM + TN) * 64;
    __shared__ __align__(16) char smem[2 * STRIDE];

    int t = threadIdx.x;
    int w = t >> 6, l = t & 63;
    int wr = w >> 1, wc = w & 1;
    int lr = l & 15, lh = l >> 4;
    int m0 = blockIdx.y * TM, n0 = blockIdx.x * TN;

    int br = t / TPR, bh = t % TPR;
    int gbr = n0 + br; if (gbr >= N) gbr = N - 1;
    const float* bbase = B + (size_t)gbr * K + bh * (SPT * 8);

    f32x4  acc[FR][FC] = {};
    float4 breg[TN / 32];
    const int nt = K >> 5;

    auto stageA = [&](int kt, int p) {
        char* dst = smem + p * STRIDE;
        #pragma unroll
        for (int i = 0; i < AI; ++i) {
            int tt   = i * 256 + t;
            int row  = tt & (TM - 1);
            int slot = tt >> LTM;
            int gr   = m0 + row;
            if (COMPACT) gr = ((gr >> 6) * SEQ) + (gr & 63);
            else if (gr >= M) gr = M - 1;
            const unsigned short* gp = A + (size_t)gr * K + kt + slot * 8;
            __builtin_amdgcn_global_load_lds(
                (const __attribute__((address_space(1))) void*)gp,
                (__attribute__((address_space(3))) void*)(dst + (size_t)(i * 256 + w * 64) * 16),
                16, 0, 0);
        }
    };
    auto loadB = [&](int kt) {
        const float* bp = bbase + kt;
        #pragma unroll
        for (int j = 0; j < TN / 32; ++j) breg[j] = *(const float4*)(bp + j * 4);
    };
    auto writeB = [&](int p) {
        unsigned short* bs = (unsigned short*)(smem + p * STRIDE + TM * 64);
        #pragma unroll
        for (int s = 0; s < SPT; ++s) {
            ushort8n u;
            #pragma unroll
            for (int e = 0; e < 8; ++e) {
                float f = ((const float*)&breg[s * 2 + (e >> 2)])[e & 3];
                u[e] = f2bf(f);
            }
            int slot = bh * SPT + s;
            *(ushort8n*)(bs + ((size_t)slot * TN + br) * 8) = u;
        }
    };
    auto compute = [&](int p) {
        const unsigned short* as_ = (const unsigned short*)(smem + p * STRIDE);
        const unsigned short* bs_ = as_ + TM * 32;
        short8 af[FR], bfv[FC];
        #pragma unroll
        for (int mi = 0; mi < FR; ++mi)
            af[mi] = *(const short8*)(as_ + ((size_t)lh * TM + wr * WRH + mi * 16 + lr) * 8);
        #pragma unroll
        for (int ni = 0; ni < FC; ++ni)
            bfv[ni] = *(const short8*)(bs_ + ((size_t)lh * TN + wc * WCH + ni * 16 + lr) * 8);
        #pragma unroll
        for (int mi = 0; mi < FR; ++mi)
            #pragma unroll
            for (int ni = 0; ni < FC; ++ni)
                acc[mi][ni] = __builtin_amdgcn_mfma_f32_16x16x32_bf16(af[mi], bfv[ni], acc[mi][ni], 0, 0, 0);
    };

    stageA(0, 0); loadB(0); writeB(0);
    __syncthreads();
    for (int it = 0; it < nt; ++it) {
        int p = it & 1;
        if (it + 1 < nt) { stageA((it + 1) << 5, 1 - p); loadB((it + 1) << 5); }
        compute(p);
        if (it + 1 < nt) writeB(1 - p);
        __syncthreads();
    }

    #pragma unroll
    for (int ni = 0; ni < FC; ++ni) {
        int gcol = n0 + wc * WCH + ni * 16 + lr;
        if (gcol >= N) continue;
        float bv = bias ? bias[gcol] : 0.f;
        #pragma unroll
        for (int mi = 0; mi < FR; ++mi)
            #pragma unroll
            for (int r = 0; r < 4; ++r) {
                int grow = m0 + wr * WRH + mi * 16 + lh * 4 + r;
                if (grow >= M) continue;
                float v = acc[mi][ni][r] + bv;
                if (RELU) v = fmaxf(v, 0.f);
                if (OUT_BF16) ((unsigned short*)C)[(size_t)grow * N + gcol] = f2bf(v);
                else          ((float*)C)[(size_t)grow * N + gcol] = v;
            }
    }
}

// ======== fused attention: block = (qhalf, h, b), 256 threads ========
#define APAD 65
__global__ __launch_bounds__(256) void attn_fused(const float* __restrict__ qkv,
                                                  unsigned short* __restrict__ ctx16) {
    int qpart = blockIdx.x;
    int h = blockIdx.y, b = blockIdx.z;
    __shared__ float Ks[SEQ * APAD];
    __shared__ float Vs[SEQ * APAD];
    __shared__ float qsh[4][64];
    __shared__ float pws[4][SEQ + 3];

    const float* base = qkv + (size_t)b * SEQ * (3 * EMB) + h * DH;
    int t = threadIdx.x;
    for (int idx = t; idx < SEQ * 16; idx += 256) {
        int r = idx >> 4, c4 = (idx & 15) << 2;
        const float* rp = base + (size_t)r * (3 * EMB);
        float4 kv = *(const float4*)(rp + EMB + c4);
        float4 vv = *(const float4*)(rp + 2 * EMB + c4);
        float* kd = Ks + r * APAD + c4;
        kd[0] = kv.x; kd[1] = kv.y; kd[2] = kv.z; kd[3] = kv.w;
        float* vd = Vs + r * APAD + c4;
        vd[0] = vv.x; vd[1] = vv.y; vd[2] = vv.z; vd[3] = vv.w;
    }
    __syncthreads();

    int w = t >> 6, l = t & 63;
    int qstart = qpart ? 33 : 0;
    int qend   = qpart ? SEQ : 33;
    for (int qi = qstart + w; qi < qend; qi += 4) {
        qsh[w][l] = base[(size_t)qi * (3 * EMB) + l];
        float s = 0.f;
        #pragma unroll 16
        for (int d = 0; d < DH; ++d) s += qsh[w][d] * Ks[l * APAD + d];
        s *= 0.125f;
        float s64 = -1e30f;
        if (l == 0) {
            float acc64 = 0.f;
            #pragma unroll 16
            for (int d = 0; d < DH; ++d) acc64 += qsh[w][d] * Ks[64 * APAD + d];
            s64 = acc64 * 0.125f;
        }
        float m = (l == 0) ? fmaxf(s, s64) : s;
        #pragma unroll
        for (int off = 32; off >= 1; off >>= 1) m = fmaxf(m, __shfl_xor(m, off));
        float e = __expf(s - m);
        pws[w][l] = e;
        float esum = e;
        if (l == 0) { float e64 = __expf(s64 - m); pws[w][64] = e64; esum += e64; }
        #pragma unroll
        for (int off = 32; off >= 1; off >>= 1) esum += __shfl_xor(esum, off);
        float inv = 1.f / esum;
        float acc = 0.f;
        #pragma unroll 13
        for (int j = 0; j < SEQ; ++j) acc += pws[w][j] * Vs[j * APAD + l];
        ctx16[((size_t)b * SEQ + qi) * EMB + h * DH + l] = f2bf(acc * inv);
    }
}

// ---------------- layernorm of (x + p)
__global__ __launch_bounds__(128) void ln_kernel(const float* __restrict__ x,
                                                 const float* __restrict__ p,
                                                 const float* __restrict__ g,
                                                 const float* __restrict__ be,
                                                 float* __restrict__ y32,
                                                 unsigned short* __restrict__ y16) {
    int row = blockIdx.x;
    int t = threadIdx.x;
    const float4 xv = ((const float4*)(x + (size_t)row * EMB))[t];
    const float4 pv = ((const float4*)(p + (size_t)row * EMB))[t];
    float v0 = xv.x + pv.x, v1 = xv.y + pv.y, v2 = xv.z + pv.z, v3 = xv.w + pv.w;
    float sum = v0 + v1 + v2 + v3;
    float sq  = v0 * v0 + v1 * v1 + v2 * v2 + v3 * v3;
    #pragma unroll
    for (int off = 32; off >= 1; off >>= 1) {
        sum += __shfl_down(sum, off);
        sq  += __shfl_down(sq,  off);
    }
    __shared__ float s0[2], s1[2];
    if ((t & 63) == 0) { s0[t >> 6] = sum; s1[t >> 6] = sq; }
    __syncthreads();
    float S = s0[0] + s0[1], Q = s1[0] + s1[1];
    float mean = S * (1.f / EMB);
    float var  = Q * (1.f / EMB) - mean * mean;
    float rstd = rsqrtf(var + 1e-5f);
    const float4 gv = ((const float4*)g)[t];
    const float4 bv = ((const float4*)be)[t];
    float4 o;
    o.x = (v0 - mean) * rstd * gv.x + bv.x;
    o.y = (v1 - mean) * rstd * gv.y + bv.y;
    o.z = (v2 - mean) * rstd * gv.z + bv.z;
    o.w = (v3 - mean) * rstd * gv.w + bv.w;
    ((float4*)(y32 + (size_t)row * EMB))[t] = o;
    ushort4 h;
    h.x = f2bf(o.x); h.y = f2bf(o.y); h.z = f2bf(o.z); h.w = f2bf(o.w);
    ((ushort4*)(y16 + (size_t)row * EMB))[t] = h;
}

extern "C" void kernel_launch(void* const* d_in, const int* in_sizes, int n_in,
                              void* d_out, int out_size, void* d_ws, size_t ws_size,
                              hipStream_t stream) {
    const float* w_emb    = (const float*)d_in[0];
    const float* table    = (const float*)d_in[1];
    const float* word_enc = (const float*)d_in[2];
    const float* Wqkv     = (const float*)d_in[3];
    const float* bqkv     = (const float*)d_in[4];
    const float* Wo       = (const float*)d_in[5];
    const float* bo       = (const float*)d_in[6];
    const float* W1       = (const float*)d_in[7];
    const float* b1       = (const float*)d_in[8];
    const float* W2       = (const float*)d_in[9];
    const float* b2       = (const float*)d_in[10];
    const float* g1       = (const float*)d_in[11];
    const float* be1      = (const float*)d_in[12];
    const float* g2       = (const float*)d_in[13];
    const float* be2      = (const float*)d_in[14];
    float* out = (float*)d_out;

    const size_t act_bytes = (size_t)TOK * EMB * 4 * 3
                           + (size_t)TOK * 3 * EMB * 4
                           + (size_t)TOK * EMB * 2 * 3
                           + (size_t)TOK * FF_ * 2;
    const size_t wgt_bytes = (size_t)CVT_TOTAL * 2;
    const bool fast = ws_size >= act_bytes + wgt_bytes;

    char* ws = (char*)d_ws;
    unsigned short* wgt16 = nullptr;
    if (fast) { wgt16 = (unsigned short*)ws; ws += wgt_bytes; }
    float* xa32  = (float*)ws;                    ws += (size_t)TOK * EMB * 4;
    float* xb32  = (float*)ws;                    ws += (size_t)TOK * EMB * 4;
    float* qkv32 = (float*)ws;                    ws += (size_t)TOK * 3 * EMB * 4;
    float* proj32= (float*)ws;                    ws += (size_t)TOK * EMB * 4;
    unsigned short* hbuf16= (unsigned short*)ws;  ws += (size_t)TOK * FF_ * 2;
    unsigned short* xa16  = (unsigned short*)ws;  ws += (size_t)TOK * EMB * 2;
    unsigned short* xb16  = (unsigned short*)ws;  ws += (size_t)TOK * EMB * 2;
    unsigned short* ctx16 = (unsigned short*)ws;  ws += (size_t)TOK * EMB * 2;
    float* projb  = qkv32;       // Wo/ff2 split-K part1 (qkv32 dead by then)

    if (fast) cvt_kernel<<<2048, 256, 0, stream>>>(Wqkv, Wo, W1, W2, table, wgt16);

    {
        int total = BS * SEQ * EMB;
        embed_kernel<<<(total + 255) / 256, 256, 0, stream>>>(w_emb, word_enc, xa32, xa16);
    }

    if (fast) {
        const unsigned short* wq16 = wgt16;
        const unsigned short* wo16 = wgt16 + O_WO;
        const unsigned short* w116 = wgt16 + O_W1;
        const unsigned short* w216 = wgt16 + O_W2;
        const unsigned short* tab16= wgt16 + O_TAB;

        for (int l = 0; l < NL; ++l) {
            // qkv: full K=512, grid 17*24=408 (div by 8)
            gemm4<64,64,64,0,0,0,0><<<dim3(408), 256, 0, stream>>>(
                xa16, wq16 + (size_t)l * 3 * EMB * EMB, bqkv + (size_t)l * 3 * EMB,
                qkv32, nullptr, nullptr, TOK, 3 * EMB, EMB, EMB, EMB);
            attn_fused<<<dim3(2, NH, BS), 256, 0, stream>>>(qkv32, ctx16);
            // Wo: split-K2 (Kp=256); res=xa32 in part0; ln sums parts
            gemm4<64,32,64,0,0,0,1><<<dim3(544), 256, 0, stream>>>(
                ctx16, wo16 + (size_t)l * EMB * EMB, bo + (size_t)l * EMB,
                proj32, projb, xa32, TOK, EMB, 256, EMB, EMB);
            ln_kernel<<<TOK, 128, 0, stream>>>(proj32, projb,
                g1 + (size_t)l * EMB, be1 + (size_t)l * EMB, xb32, xb16);
            // ff1: full K=512, relu, bf16 out
            gemm4<64,64,64,1,1,0,0><<<dim3(544), 256, 0, stream>>>(
                xb16, w116 + (size_t)l * FF_ * EMB, b1 + (size_t)l * FF_,
                hbuf16, nullptr, nullptr, TOK, FF_, EMB, EMB, EMB);
            // ff2: split-K2 (Kp=1024); res=xb32 in part0
            gemm4<64,32,64,0,0,0,1><<<dim3(544), 256, 0, stream>>>(
                hbuf16, w216 + (size_t)l * EMB * FF_, b2 + (size_t)l * EMB,
                proj32, projb, xb32, TOK, EMB, 1024, FF_, FF_);
            ln_kernel<<<TOK, 128, 0, stream>>>(proj32, projb,
                g2 + (size_t)l * EMB, be2 + (size_t)l * EMB, xa32, xa16);
        }
        // logits: 256x256 tile, 512 threads, grid 4*197=788 (bijective swizzle)
        gemm5<<<dim3(4 * ((VOCAB + 255) / 256)), 512, 0, stream>>>(
            xa16, tab16, out, TOUT, VOCAB, EMB);
    } else {
        for (int l = 0; l < NL; ++l) {
            const float* Wqkv_l = Wqkv + (size_t)l * 3 * EMB * EMB;
            const float* Wo_l   = Wo   + (size_t)l * EMB * EMB;
            const float* W1_l   = W1   + (size_t)l * FF_ * EMB;
            const float* W2_l   = W2   + (size_t)l * EMB * FF_;
            gemm2<64,64,0,0,0><<<dim3((3 * EMB) / 64, (TOK + 63) / 64), 256, 0, stream>>>(
                xa16, Wqkv_l, bqkv + (size_t)l * 3 * EMB, qkv32, TOK, 3 * EMB, EMB);
            attn_fused<<<dim3(2, NH, BS), 256, 0, stream>>>(qkv32, ctx16);
            gemm2<64,64,0,0,0><<<dim3(EMB / 64, (TOK + 63) / 64), 256, 0, stream>>>(
                ctx16, Wo_l, bo + (size_t)l * EMB, proj32, TOK, EMB, EMB);
            ln_kernel<<<TOK, 128, 0, stream>>>(xa32, proj32, g1 + (size_t)l * EMB, be1 + (size_t)l * EMB, xb32, xb16);
            gemm2<64,64,1,1,0><<<dim3(FF_ / 64, (TOK + 63) / 64), 256, 0, stream>>>(
                xb16, W1_l, b1 + (size_t)l * FF_, hbuf16, TOK, FF_, EMB);
            gemm2<64,64,0,0,0><<<dim3(EMB / 64, (TOK + 63) / 64), 256, 0, stream>>>(
                hbuf16, W2_l, b2 + (size_t)l * EMB, proj32, TOK, EMB, FF_);
            ln_kernel<<<TOK, 128, 0, stream>>>(xb32, proj32, g2 + (size_t)l * EMB, be2 + (size_t)l * EMB, xa32, xa16);
        }
        gemm2<128,128,0,0,1><<<dim3((VOCAB + 127) / 128, TOUT / 128), 256, 0, stream>>>(
            xa16, table, nullptr, out, TOUT, VOCAB, EMB);
    }
}